// Round 3
// baseline (331.019 us; speedup 1.0000x reference)
//
#include <hip/hip_runtime.h>
#include <hip/hip_bf16.h>

// RewardCLIP loss:
//   diff[i] = dot(input_embs[i] - neg_input_embs[i], image_embs[i])
//   loss = -mean(log_sigmoid(diff * alpha))
//
// Memory-bound: 3 x 65536 x 1024 x 4B = 768 MiB read; effective BW at R1 was
// 5.75 TB/s (91% of achievable). R2 change: fuse the finalize dispatch into
// the main kernel via last-block-done (device-scope atomic counter), removing
// ~4-7us of serial launch tail. Agent-scope atomics for partials to avoid
// stale per-XCD L2 lines from the previous graph replay.

#define DIMS 1024
#define BLOCKS 2048
#define THREADS 256
#define WAVES_PER_BLOCK (THREADS / 64)
#define ROWS_PER_WAVE 8   // 2048 blocks * 4 waves * 8 rows = 65536

__global__ __launch_bounds__(THREADS) void rewardclip_fused(
    const float* __restrict__ a,      // input_embs
    const float* __restrict__ b,      // neg_input_embs
    const float* __restrict__ c,      // image_embs
    const int* __restrict__ alpha_p,  // scalar (python int)
    int rows,
    float* __restrict__ partials,     // [BLOCKS] in d_ws
    unsigned* __restrict__ counter,   // zeroed via hipMemsetAsync each launch
    float* __restrict__ out) {
  const int tid  = threadIdx.x;
  const int lane = tid & 63;
  const int wave = tid >> 6;
  const int gwave = blockIdx.x * WAVES_PER_BLOCK + wave;

  const float alpha = (float)(*alpha_p);

  float acc = 0.0f;  // lane-0-valid accumulator of log_sigmoid values

  const int row0 = gwave * ROWS_PER_WAVE;
#pragma unroll 1
  for (int r = 0; r < ROWS_PER_WAVE; ++r) {
    const int row = row0 + r;
    if (row >= rows) break;
    const float4* __restrict__ pa = (const float4*)(a + (size_t)row * DIMS) + lane;
    const float4* __restrict__ pb = (const float4*)(b + (size_t)row * DIMS) + lane;
    const float4* __restrict__ pc = (const float4*)(c + (size_t)row * DIMS) + lane;

    const float4 a0 = pa[0], a1 = pa[64], a2 = pa[128], a3 = pa[192];
    const float4 b0 = pb[0], b1 = pb[64], b2 = pb[128], b3 = pb[192];
    const float4 c0 = pc[0], c1 = pc[64], c2 = pc[128], c3 = pc[192];

    float d0 = 0.f, d1 = 0.f, d2 = 0.f, d3 = 0.f;
    d0 += (a0.x - b0.x) * c0.x; d0 += (a0.y - b0.y) * c0.y;
    d0 += (a0.z - b0.z) * c0.z; d0 += (a0.w - b0.w) * c0.w;
    d1 += (a1.x - b1.x) * c1.x; d1 += (a1.y - b1.y) * c1.y;
    d1 += (a1.z - b1.z) * c1.z; d1 += (a1.w - b1.w) * c1.w;
    d2 += (a2.x - b2.x) * c2.x; d2 += (a2.y - b2.y) * c2.y;
    d2 += (a2.z - b2.z) * c2.z; d2 += (a2.w - b2.w) * c2.w;
    d3 += (a3.x - b3.x) * c3.x; d3 += (a3.y - b3.y) * c3.y;
    d3 += (a3.z - b3.z) * c3.z; d3 += (a3.w - b3.w) * c3.w;

    float d = (d0 + d1) + (d2 + d3);

#pragma unroll
    for (int off = 32; off > 0; off >>= 1) d += __shfl_down(d, off, 64);

    if (lane == 0) {
      const float x = d * alpha;
      const float ls = fminf(x, 0.0f) - log1pf(__expf(-fabsf(x)));
      acc += ls;
    }
  }

  __shared__ float s[WAVES_PER_BLOCK];
  __shared__ unsigned last_flag;
  if (lane == 0) s[wave] = acc;
  __syncthreads();

  if (tid == 0) {
    float t = 0.0f;
#pragma unroll
    for (int w = 0; w < WAVES_PER_BLOCK; ++w) t += s[w];
    // Device-visible release of this block's partial, then count completion.
    __hip_atomic_store(&partials[blockIdx.x], t, __ATOMIC_RELEASE,
                       __HIP_MEMORY_SCOPE_AGENT);
    const unsigned prev = __hip_atomic_fetch_add(
        counter, 1u, __ATOMIC_ACQ_REL, __HIP_MEMORY_SCOPE_AGENT);
    last_flag = (prev == gridDim.x - 1) ? 1u : 0u;
  }
  __syncthreads();

  if (last_flag) {
    // Last block reduces all partials. Agent-scope loads so we never read a
    // stale line from this XCD's (non-coherent) L2 left by a prior replay.
    float ssum = 0.0f;
    for (int i = tid; i < BLOCKS; i += THREADS)
      ssum += __hip_atomic_load(&partials[i], __ATOMIC_RELAXED,
                                __HIP_MEMORY_SCOPE_AGENT);
#pragma unroll
    for (int off = 32; off > 0; off >>= 1) ssum += __shfl_down(ssum, off, 64);

    __shared__ float ws2[WAVES_PER_BLOCK];
    if (lane == 0) ws2[wave] = ssum;
    __syncthreads();
    if (tid == 0) {
      float t = 0.0f;
#pragma unroll
      for (int w = 0; w < WAVES_PER_BLOCK; ++w) t += ws2[w];
      out[0] = -t / (float)rows;
    }
  }
}

extern "C" void kernel_launch(void* const* d_in, const int* in_sizes, int n_in,
                              void* d_out, int out_size, void* d_ws, size_t ws_size,
                              hipStream_t stream) {
  const float* a = (const float*)d_in[0];       // input_embs
  const float* b = (const float*)d_in[1];       // neg_input_embs
  const float* c = (const float*)d_in[2];       // image_embs
  const int* alpha_p = (const int*)d_in[3];     // python int scalar

  const int rows = in_sizes[0] / DIMS;          // 65536

  // d_ws layout: [0..3] counter (uint32), [256 ..] partials (BLOCKS floats)
  unsigned* counter = (unsigned*)d_ws;
  float* partials   = (float*)((char*)d_ws + 256);
  float* out        = (float*)d_out;

  hipMemsetAsync(counter, 0, sizeof(unsigned), stream);  // graph-capturable
  rewardclip_fused<<<BLOCKS, THREADS, 0, stream>>>(a, b, c, alpha_p, rows,
                                                   partials, counter, out);
}

// Round 4
// 149.071 us; speedup vs baseline: 2.2206x; 2.2206x over previous
//
#include <hip/hip_runtime.h>
#include <hip/hip_bf16.h>

// RewardCLIP loss:
//   diff[i] = dot(input_embs[i] - neg_input_embs[i], image_embs[i])
//   loss = -mean(log_sigmoid(diff * alpha))
//
// Memory-bound: 3 x 65536 x 1024 x 4B = 768 MiB read. Main loop runs at
// ~6.0 TB/s effective (~95% of the 6.29 TB/s copy ceiling).
// R3 change vs R2: drop the acquire/release last-block-done (it invalidated
// L2 per block -> 2.3x regression). Instead: single kernel, each block does
// ONE relaxed device-scope float atomicAdd of its pre-scaled partial into
// out[0]; out[0] zeroed via hipMemsetAsync each launch. No second dispatch,
// no cache-flushing semantics.

#define DIMS 1024
#define BLOCKS 2048
#define THREADS 256
#define WAVES_PER_BLOCK (THREADS / 64)

__global__ __launch_bounds__(THREADS) void rewardclip_main(
    const float* __restrict__ a,      // input_embs
    const float* __restrict__ b,      // neg_input_embs
    const float* __restrict__ c,      // image_embs
    const int* __restrict__ alpha_p,  // scalar (python int)
    int rows,
    float* __restrict__ out) {
  const int tid  = threadIdx.x;
  const int lane = tid & 63;
  const int wave = tid >> 6;
  const int gwave  = blockIdx.x * WAVES_PER_BLOCK + wave;
  const int nwaves = gridDim.x * WAVES_PER_BLOCK;

  const float alpha = (float)(*alpha_p);

  float acc = 0.0f;  // lane-0-valid accumulator of log_sigmoid values

  for (int row = gwave; row < rows; row += nwaves) {
    const float4* __restrict__ pa = (const float4*)(a + (size_t)row * DIMS) + lane;
    const float4* __restrict__ pb = (const float4*)(b + (size_t)row * DIMS) + lane;
    const float4* __restrict__ pc = (const float4*)(c + (size_t)row * DIMS) + lane;

    const float4 a0 = pa[0], a1 = pa[64], a2 = pa[128], a3 = pa[192];
    const float4 b0 = pb[0], b1 = pb[64], b2 = pb[128], b3 = pb[192];
    const float4 c0 = pc[0], c1 = pc[64], c2 = pc[128], c3 = pc[192];

    float d0 = 0.f, d1 = 0.f, d2 = 0.f, d3 = 0.f;
    d0 += (a0.x - b0.x) * c0.x; d0 += (a0.y - b0.y) * c0.y;
    d0 += (a0.z - b0.z) * c0.z; d0 += (a0.w - b0.w) * c0.w;
    d1 += (a1.x - b1.x) * c1.x; d1 += (a1.y - b1.y) * c1.y;
    d1 += (a1.z - b1.z) * c1.z; d1 += (a1.w - b1.w) * c1.w;
    d2 += (a2.x - b2.x) * c2.x; d2 += (a2.y - b2.y) * c2.y;
    d2 += (a2.z - b2.z) * c2.z; d2 += (a2.w - b2.w) * c2.w;
    d3 += (a3.x - b3.x) * c3.x; d3 += (a3.y - b3.y) * c3.y;
    d3 += (a3.z - b3.z) * c3.z; d3 += (a3.w - b3.w) * c3.w;

    float d = (d0 + d1) + (d2 + d3);

    // 64-lane shuffle reduction
#pragma unroll
    for (int off = 32; off > 0; off >>= 1) d += __shfl_down(d, off, 64);

    if (lane == 0) {
      const float x = d * alpha;
      const float ls = fminf(x, 0.0f) - log1pf(__expf(-fabsf(x)));
      acc += ls;
    }
  }

  __shared__ float s[WAVES_PER_BLOCK];
  if (lane == 0) s[wave] = acc;
  __syncthreads();
  if (tid == 0) {
    float t = 0.0f;
#pragma unroll
    for (int w = 0; w < WAVES_PER_BLOCK; ++w) t += s[w];
    // One fire-and-forget device-scope atomic per block; pre-scaled so no
    // finalize kernel is needed. out[0] is zeroed by memsetAsync per launch.
    atomicAdd(out, t * (-1.0f / (float)rows));
  }
}

extern "C" void kernel_launch(void* const* d_in, const int* in_sizes, int n_in,
                              void* d_out, int out_size, void* d_ws, size_t ws_size,
                              hipStream_t stream) {
  const float* a = (const float*)d_in[0];       // input_embs
  const float* b = (const float*)d_in[1];       // neg_input_embs
  const float* c = (const float*)d_in[2];       // image_embs
  const int* alpha_p = (const int*)d_in[3];     // python int scalar

  const int rows = in_sizes[0] / DIMS;          // 65536
  float* out = (float*)d_out;

  hipMemsetAsync(out, 0, sizeof(float), stream);  // graph-capturable
  rewardclip_main<<<BLOCKS, THREADS, 0, stream>>>(a, b, c, alpha_p, rows, out);
}